// Round 6
// baseline (236.808 us; speedup 1.0000x reference)
//
#include <hip/hip_runtime.h>
#include <hip/hip_fp16.h>

#define BATCH 8192
#define FDIM  512
#define NTREE 64
#define NODES 63
#define ODIM  128
#define NJP   4096            // padded N: col c = t*64 + n, n=63 is pad
#define K2    4096            // leaf GEMM K: k = t*64 + l

typedef _Float16 f16;
typedef _Float16 f16x8 __attribute__((ext_vector_type(8)));
typedef float    f32x4 __attribute__((ext_vector_type(4)));

// ---------------- workspace layout (bytes) ----------------
#define XH_OFF   0
#define XH_SZ    ((size_t)BATCH*FDIM*2)        // 8.39 MB  x  f16 [b][f]
#define WNH_OFF  (XH_OFF + XH_SZ)
#define WNH_SZ   ((size_t)NJP*FDIM*2)          // 4.19 MB  Wn f16 [t*64+n][f]
#define WLT_OFF  (WNH_OFF + WNH_SZ)
#define WLT_SZ   ((size_t)ODIM*K2*2)           // 1.05 MB  Wl f16 [o][t*64+l]
#define SP_OFF   (WLT_OFF + WLT_SZ)
#define SP_SZ    ((size_t)BATCH*NJP*2)         // 67.1 MB  s/prob f16 [b][t*64+n]
#define WS_NEEDED (SP_OFF + SP_SZ)

__device__ __forceinline__ float smooth_step_f(float t) {
    float tc = fminf(fmaxf(t, -0.5f), 0.5f);
    return fmaf(tc, fmaf(-2.0f * tc, tc, 1.5f), 0.5f);
}

__device__ __forceinline__ void async16(const void* g, void* l) {
    __builtin_amdgcn_global_load_lds((__attribute__((address_space(1))) void*)g,
                                     (__attribute__((address_space(3))) void*)l,
                                     16, 0, 0);
}

// swizzled f16 offset of (row, group g) in a [rows][64] tile staged as 1KB/8-row chunks
__device__ __forceinline__ int sw_off(int row, int g) {
    return ((row >> 3) * 512) + (((row & 7) * 8 + (g ^ (row & 7))) * 8);
}

// ---------------- conversions ----------------
__global__ void conv_x_kernel(const float* __restrict__ in, f16* __restrict__ out) {
    size_t i = ((size_t)blockIdx.x * blockDim.x + threadIdx.x) * 4;
    float4 v = *(const float4*)(in + i);
    f16* o = out + i;
    o[0] = (f16)v.x; o[1] = (f16)v.y; o[2] = (f16)v.z; o[3] = (f16)v.w;
}

// Wl[l][o][t] fp32 -> wlt[o][t*64+l] f16 ; one block per o
__global__ void conv_wl_kernel(const float* __restrict__ in, f16* __restrict__ out) {
    __shared__ f16 tile[64][72];          // [t][l], padded
    const int o    = blockIdx.x;          // 0..127
    const int lane = threadIdx.x & 63;    // t on read
    const int w    = threadIdx.x >> 6;
    #pragma unroll
    for (int lc = 0; lc < 16; ++lc) {
        int l = w * 16 + lc;
        tile[lane][l] = (f16)in[(size_t)l * (ODIM * NTREE) + o * 64 + lane];  // coalesced
    }
    __syncthreads();
    f16* orow = out + (size_t)o * K2;
    #pragma unroll
    for (int c = 0; c < 2; ++c) {
        int idx = (threadIdx.x * 2 + c) * 8;   // 0..4088
        int t = idx >> 6, l = idx & 63;
        f16x8 v;
        #pragma unroll
        for (int e = 0; e < 8; ++e) v[e] = tile[t][l + e];
        *(f16x8*)(orow + idx) = v;             // fully coalesced
    }
}

// Wn[n][f][t] fp32 -> wnh[(t*64+n)][f] f16 ; block n==63 zeros pad rows
__global__ void conv_wn_kernel(const float* __restrict__ wn, f16* __restrict__ out) {
    const int n    = blockIdx.x;          // 0..63 (63 = pad)
    const int f0   = blockIdx.y * 64;
    const int lane = threadIdx.x & 63;
    const int w    = threadIdx.x >> 6;
    if (n == NODES) {
        #pragma unroll
        for (int tc = 0; tc < 16; ++tc) {
            int t = w * 16 + tc;
            out[(size_t)(t * 64 + NODES) * FDIM + f0 + lane] = (f16)0.0f;
        }
        return;
    }
    __shared__ float tile[64][65];
    const float* src = wn + (size_t)n * (FDIM * NTREE);
    #pragma unroll
    for (int i = 0; i < 16; ++i) {
        int fl = w * 16 + i;
        tile[fl][lane] = src[(size_t)(f0 + fl) * NTREE + lane];
    }
    __syncthreads();
    #pragma unroll
    for (int i = 0; i < 16; ++i) {
        int t = w * 16 + i;
        out[(size_t)(t * 64 + n) * FDIM + f0 + lane] = (f16)tile[lane][t];
    }
}

// ---------------- phase 1: node GEMM (M=8192, N=4096, K=512) + bias + smooth_step ----------------
__global__ __launch_bounds__(256, 3)
void gemm_nodes(const f16* __restrict__ xh, const f16* __restrict__ wnh,
                const float* __restrict__ bn, f16* __restrict__ s_out)
{
    __shared__ f16 SH[128 * 128];         // 32 KB: staging A+B, then C-tile
    f16* Ash = SH;
    f16* Bsh = SH + 128 * 64;
    const int tid  = threadIdx.x;
    const int lane = tid & 63;
    const int w    = tid >> 6;
    const int wm   = w & 1;
    const int wn   = w >> 1;
    const int j0   = blockIdx.x * 128;
    const int row0 = blockIdx.y * 128;

    const int lr = lane >> 3;
    const int lg = (lane & 7) ^ lr;
    f32x4 acc[4][4] = {};

    for (int k0 = 0; k0 < FDIM; k0 += 64) {
        #pragma unroll
        for (int q = 0; q < 8; ++q) {
            int id = w * 8 + q;
            if (id < 16) {
                int r = id * 8 + lr;
                async16(xh + (size_t)(row0 + r) * FDIM + k0 + lg * 8, &Ash[id * 512 + lane * 8]);
            } else {
                int c = id - 16;
                int r = c * 8 + lr;
                async16(wnh + (size_t)(j0 + r) * FDIM + k0 + lg * 8, &Bsh[c * 512 + lane * 8]);
            }
        }
        __syncthreads();
        #pragma unroll
        for (int ks = 0; ks < 2; ++ks) {
            int g = ks * 4 + (lane >> 4);
            f16x8 bfr[4];
            #pragma unroll
            for (int tn = 0; tn < 4; ++tn) {
                int j = wn * 64 + tn * 16 + (lane & 15);
                bfr[tn] = *(const f16x8*)&Bsh[sw_off(j, g)];
            }
            #pragma unroll
            for (int tm = 0; tm < 4; ++tm) {
                int m = wm * 64 + tm * 16 + (lane & 15);
                f16x8 afr = *(const f16x8*)&Ash[sw_off(m, g)];
                #pragma unroll
                for (int tn = 0; tn < 4; ++tn)
                    acc[tm][tn] = __builtin_amdgcn_mfma_f32_16x16x32_f16(afr, bfr[tn], acc[tm][tn], 0, 0, 0);
            }
        }
        __syncthreads();
    }

    // epilogue: bias+smooth_step into LDS C-tile (swizzled), then coalesced stores
    #pragma unroll
    for (int tn = 0; tn < 4; ++tn) {
        int col = wn * 64 + tn * 16 + (lane & 15);
        int c   = j0 + col;                 // c = t*64 + n
        int nn  = c & 63, tt = c >> 6;
        float bias = (nn < NODES) ? bn[nn * NTREE + tt] : 0.0f;
        #pragma unroll
        for (int tm = 0; tm < 4; ++tm) {
            #pragma unroll
            for (int r = 0; r < 4; ++r) {
                int row = wm * 64 + tm * 16 + (lane >> 4) * 4 + r;
                float v = acc[tm][tn][r] + bias;
                int scol = col ^ (((row >> 2) & 3) << 4);
                SH[row * 128 + scol] = (f16)smooth_step_f(v);
            }
        }
    }
    __syncthreads();
    const int4* shv = (const int4*)SH;
    #pragma unroll
    for (int it = 0; it < 8; ++it) {
        int idx = it * 256 + tid;
        int row = idx >> 4, c = idx & 15;
        int src = (row << 4) + (c ^ (((row >> 2) & 3) << 1));
        ((int4*)(s_out + (size_t)(row0 + row) * NJP + j0))[c] = shv[src];
    }
}

// ---------------- phase 2: prob, register-resident streaming, in place ----------------
// thread = (row, t); gates for (row,t) are contiguous: sp[row*4096 + t*64 + n]
__global__ __launch_bounds__(256)
void prob_kernel(f16* __restrict__ sp)
{
    const int lane = threadIdx.x & 63;               // t
    const int w    = threadIdx.x >> 6;
    const size_t row = (size_t)blockIdx.x * 4 + w;
    f16* base = sp + row * NJP + lane * 64;

    f16x8 gv[8];
    #pragma unroll
    for (int c = 0; c < 8; ++c) gv[c] = ((const f16x8*)base)[c];
    float g[64];
    #pragma unroll
    for (int c = 0; c < 8; ++c)
        #pragma unroll
        for (int e = 0; e < 8; ++e) g[c * 8 + e] = (float)gv[c][e];

    float pr[32];
    pr[0] = 1.0f;
    int bse = 0;
    #pragma unroll
    for (int lvl = 0; lvl < 5; ++lvl) {
        const int width = 1 << lvl;
        #pragma unroll
        for (int i = width - 1; i >= 0; --i) {
            float p = pr[i], s = g[bse + i];
            pr[2 * i]     = p * s;
            pr[2 * i + 1] = p * (1.0f - s);
        }
        bse += width;
    }
    f16x8 ov[8];
    #pragma unroll
    for (int i = 0; i < 32; ++i) {
        float p = pr[i], s = g[31 + i];
        ov[i >> 2][(i & 3) * 2]     = (f16)(p * s);
        ov[i >> 2][(i & 3) * 2 + 1] = (f16)(p * (1.0f - s));
    }
    #pragma unroll
    for (int c = 0; c < 8; ++c) ((f16x8*)base)[c] = ov[c];
}

// ---------------- phase 3: leaf GEMM (M=8192, N=128, K=4096), barrier-free ----------------
// block = 16 rows (A lines shared via L1); wave w = cols [w*32, w*32+32)
__global__ __launch_bounds__(256)
void leaf_gemm(const f16* __restrict__ prob, const f16* __restrict__ wlt,
               float* __restrict__ out)
{
    const int lane = threadIdx.x & 63;
    const int w    = threadIdx.x >> 6;
    const int row0 = blockIdx.x * 16;
    const int o0   = w * 32;
    const int m = lane & 15, q = lane >> 4;

    const f16* ap  = prob + (size_t)(row0 + m) * NJP + q * 8;
    const f16* bp0 = wlt + (size_t)(o0 + m) * K2 + q * 8;
    const f16* bp1 = bp0 + (size_t)16 * K2;

    f32x4 acc[2] = {};
    #pragma unroll 4
    for (int k = 0; k < K2; k += 32) {
        f16x8 af  = *(const f16x8*)(ap + k);
        f16x8 bf0 = *(const f16x8*)(bp0 + k);
        f16x8 bf1 = *(const f16x8*)(bp1 + k);
        acc[0] = __builtin_amdgcn_mfma_f32_16x16x32_f16(af, bf0, acc[0], 0, 0, 0);
        acc[1] = __builtin_amdgcn_mfma_f32_16x16x32_f16(af, bf1, acc[1], 0, 0, 0);
    }
    #pragma unroll
    for (int tn = 0; tn < 2; ++tn) {
        int o = o0 + tn * 16 + m;
        #pragma unroll
        for (int r = 0; r < 4; ++r)
            out[(size_t)(row0 + q * 4 + r) * ODIM + o] = acc[tn][r];
    }
}

// ---------------- fallback (round-1 proven kernel) ----------------
#define ROWS 8
__global__ __launch_bounds__(256, 2)
void soft_tree_fallback(const float* __restrict__ x, const float* __restrict__ Wn,
                        const float* __restrict__ bn, const float* __restrict__ Wl,
                        float* __restrict__ out)
{
    __shared__ __half s_lds[ROWS][NODES][NTREE];
    const int lane = threadIdx.x & 63;
    const int w    = threadIdx.x >> 6;
    const long row0 = (long)blockIdx.x * ROWS;
    for (int n = w; n < NODES; n += 4) {
        const float* wp = Wn + ((long)n * FDIM) * NTREE + lane;
        const float* xp = x + row0 * FDIM;
        float acc[ROWS];
        #pragma unroll
        for (int r = 0; r < ROWS; ++r) acc[r] = 0.0f;
        #pragma unroll 8
        for (int f = 0; f < FDIM; ++f) {
            float wv = wp[(long)f * NTREE];
            #pragma unroll
            for (int r = 0; r < ROWS; ++r)
                acc[r] = fmaf(xp[r * FDIM + f], wv, acc[r]);
        }
        float bias = bn[n * NTREE + lane];
        #pragma unroll
        for (int r = 0; r < ROWS; ++r)
            s_lds[r][n][lane] = __float2half(smooth_step_f(acc[r] + bias));
    }
    __syncthreads();
    const int r0 = w * 2, r1 = w * 2 + 1;
    float pr0[64], pr1[64];
    {
        pr0[0] = 1.0f; pr1[0] = 1.0f;
        int base = 0;
        #pragma unroll
        for (int lvl = 0; lvl < 6; ++lvl) {
            const int width = 1 << lvl;
            #pragma unroll
            for (int i = width - 1; i >= 0; --i) {
                float sa = __half2float(s_lds[r0][base + i][lane]);
                float sb = __half2float(s_lds[r1][base + i][lane]);
                float pa = pr0[i], pb = pr1[i];
                pr0[2 * i] = pa * sa; pr0[2 * i + 1] = pa * (1.0f - sa);
                pr1[2 * i] = pb * sb; pr1[2 * i + 1] = pb * (1.0f - sb);
            }
            base += width;
        }
    }
    for (int o = 0; o < ODIM; ++o) {
        const float* wlp = Wl + (long)o * NTREE + lane;
        float c0 = 0.0f, c1 = 0.0f;
        #pragma unroll
        for (int l = 0; l < 64; ++l) {
            float wv = wlp[(long)l * (ODIM * NTREE)];
            c0 = fmaf(pr0[l], wv, c0);
            c1 = fmaf(pr1[l], wv, c1);
        }
        #pragma unroll
        for (int off = 32; off > 0; off >>= 1) {
            c0 += __shfl_xor(c0, off, 64);
            c1 += __shfl_xor(c1, off, 64);
        }
        if (lane == 0) {
            out[(row0 + r0) * ODIM + o] = c0;
            out[(row0 + r1) * ODIM + o] = c1;
        }
    }
}

extern "C" void kernel_launch(void* const* d_in, const int* in_sizes, int n_in,
                              void* d_out, int out_size, void* d_ws, size_t ws_size,
                              hipStream_t stream) {
    const float* x  = (const float*)d_in[0];
    const float* Wn = (const float*)d_in[1];
    const float* bn = (const float*)d_in[2];
    const float* Wl = (const float*)d_in[3];
    float* out = (float*)d_out;

    if (ws_size < WS_NEEDED) {
        soft_tree_fallback<<<BATCH / ROWS, 256, 0, stream>>>(x, Wn, bn, Wl, out);
        return;
    }

    f16* xh  = (f16*)((char*)d_ws + XH_OFF);
    f16* wnh = (f16*)((char*)d_ws + WNH_OFF);
    f16* wlt = (f16*)((char*)d_ws + WLT_OFF);
    f16* sp  = (f16*)((char*)d_ws + SP_OFF);

    conv_x_kernel <<<(BATCH * FDIM) / (256 * 4), 256, 0, stream>>>(x, xh);
    conv_wl_kernel<<<ODIM, 256, 0, stream>>>(Wl, wlt);
    conv_wn_kernel<<<dim3(64, FDIM / 64), 256, 0, stream>>>(Wn, wnh);

    gemm_nodes<<<dim3(NJP / 128, BATCH / 128), 256, 0, stream>>>(xh, wnh, bn, sp);
    prob_kernel<<<BATCH / 4, 256, 0, stream>>>(sp);
    leaf_gemm<<<BATCH / 16, 256, 0, stream>>>(sp, wlt, out);
}

// Round 7
// 189.191 us; speedup vs baseline: 1.2517x; 1.2517x over previous
//
#include <hip/hip_runtime.h>
#include <hip/hip_fp16.h>

#define BATCH 8192
#define FDIM  512
#define NTREE 64
#define NODES 63
#define ODIM  128
#define NJP   4096            // padded N: col c = t*64 + n, n=63 is pad
#define K2    4096            // leaf GEMM K: k = t*64 + l
#define KS    4               // leaf split-K factor

typedef _Float16 f16;
typedef _Float16 f16x8 __attribute__((ext_vector_type(8)));
typedef float    f32x4 __attribute__((ext_vector_type(4)));

// ---------------- workspace layout (bytes) ----------------
#define XH_OFF   0
#define XH_SZ    ((size_t)BATCH*FDIM*2)        // 8.39 MB  x  f16 [b][f]
#define WNH_OFF  (XH_OFF + XH_SZ)
#define WNH_SZ   ((size_t)NJP*FDIM*2)          // 4.19 MB  Wn f16 [t*64+n][f]
#define WLT_OFF  (WNH_OFF + WNH_SZ)
#define WLT_SZ   ((size_t)ODIM*K2*2)           // 1.05 MB  Wl f16 [o][t*64+l]
#define SP_OFF   (WLT_OFF + WLT_SZ)
#define SP_SZ    ((size_t)BATCH*NJP*2)         // 67.1 MB  prob f16 [b][t*64+l]
#define PS_OFF   (SP_OFF + SP_SZ)
#define PS_SZ    ((size_t)KS*BATCH*ODIM*4)     // 16.8 MB  leaf split-K f32 partials
#define WS_MIN   (SP_OFF + SP_SZ)
#define WS_FULL  (PS_OFF + PS_SZ)

__device__ __forceinline__ float smooth_step_f(float t) {
    float tc = fminf(fmaxf(t, -0.5f), 0.5f);
    return fmaf(tc, fmaf(-2.0f * tc, tc, 1.5f), 0.5f);
}

__device__ __forceinline__ void async16(const void* g, void* l) {
    __builtin_amdgcn_global_load_lds((__attribute__((address_space(1))) void*)g,
                                     (__attribute__((address_space(3))) void*)l,
                                     16, 0, 0);
}

// swizzled f16 offset of (row, group g) in a [rows][64] tile staged as 1KB/8-row chunks
__device__ __forceinline__ int sw_off(int row, int g) {
    return ((row >> 3) * 512) + (((row & 7) * 8 + (g ^ (row & 7))) * 8);
}

// ---------------- conversions ----------------
__global__ void conv_x_kernel(const float* __restrict__ in, f16* __restrict__ out) {
    size_t i = ((size_t)blockIdx.x * blockDim.x + threadIdx.x) * 4;
    float4 v = *(const float4*)(in + i);
    f16* o = out + i;
    o[0] = (f16)v.x; o[1] = (f16)v.y; o[2] = (f16)v.z; o[3] = (f16)v.w;
}

// Wl[l][o][t] fp32 -> wlt[o][t*64+l] f16 ; one block per o
__global__ void conv_wl_kernel(const float* __restrict__ in, f16* __restrict__ out) {
    __shared__ f16 tile[64][72];          // [t][l], padded
    const int o    = blockIdx.x;          // 0..127
    const int lane = threadIdx.x & 63;    // t on read
    const int w    = threadIdx.x >> 6;
    #pragma unroll
    for (int lc = 0; lc < 16; ++lc) {
        int l = w * 16 + lc;
        tile[lane][l] = (f16)in[(size_t)l * (ODIM * NTREE) + o * 64 + lane];  // coalesced
    }
    __syncthreads();
    f16* orow = out + (size_t)o * K2;
    #pragma unroll
    for (int c = 0; c < 2; ++c) {
        int idx = (threadIdx.x * 2 + c) * 8;   // 0..4088
        int t = idx >> 6, l = idx & 63;
        f16x8 v;
        #pragma unroll
        for (int e = 0; e < 8; ++e) v[e] = tile[t][l + e];
        *(f16x8*)(orow + idx) = v;             // fully coalesced
    }
}

// Wn[n][f][t] fp32 -> wnh[(t*64+n)][f] f16 ; block n==63 zeros pad rows
__global__ void conv_wn_kernel(const float* __restrict__ wn, f16* __restrict__ out) {
    const int n    = blockIdx.x;          // 0..63 (63 = pad)
    const int f0   = blockIdx.y * 64;
    const int lane = threadIdx.x & 63;
    const int w    = threadIdx.x >> 6;
    if (n == NODES) {
        #pragma unroll
        for (int tc = 0; tc < 16; ++tc) {
            int t = w * 16 + tc;
            out[(size_t)(t * 64 + NODES) * FDIM + f0 + lane] = (f16)0.0f;
        }
        return;
    }
    __shared__ float tile[64][65];
    const float* src = wn + (size_t)n * (FDIM * NTREE);
    #pragma unroll
    for (int i = 0; i < 16; ++i) {
        int fl = w * 16 + i;
        tile[fl][lane] = src[(size_t)(f0 + fl) * NTREE + lane];
    }
    __syncthreads();
    #pragma unroll
    for (int i = 0; i < 16; ++i) {
        int t = w * 16 + i;
        out[(size_t)(t * 64 + n) * FDIM + f0 + lane] = (f16)tile[lane][t];
    }
}

// ---------------- phase 1: node GEMM + bias + smooth_step + PROB FOLD fused ----------------
// Tile = 128 rows x 128 cols = 2 complete trees. Epilogue folds gates -> leaf probs
// and writes prob (not s) to global. s never touches HBM.
__global__ __launch_bounds__(256, 3)
void gemm_nodes(const f16* __restrict__ xh, const f16* __restrict__ wnh,
                const float* __restrict__ bn, f16* __restrict__ prob_out)
{
    __shared__ f16 SH[128 * 130];         // 33.3 KB: staging A+B (32 KB), then C-tile [128][130]
    f16* Ash = SH;
    f16* Bsh = SH + 128 * 64;
    const int tid  = threadIdx.x;
    const int lane = tid & 63;
    const int w    = tid >> 6;
    const int wm   = w & 1;
    const int wn   = w >> 1;
    const int j0   = blockIdx.x * 128;    // cols j0..j0+127 = trees 2bx, 2bx+1 (all nodes)
    const int row0 = blockIdx.y * 128;

    const int lr = lane >> 3;
    const int lg = (lane & 7) ^ lr;
    f32x4 acc[4][4] = {};

    for (int k0 = 0; k0 < FDIM; k0 += 64) {
        #pragma unroll
        for (int q = 0; q < 8; ++q) {
            int id = w * 8 + q;
            if (id < 16) {
                int r = id * 8 + lr;
                async16(xh + (size_t)(row0 + r) * FDIM + k0 + lg * 8, &Ash[id * 512 + lane * 8]);
            } else {
                int c = id - 16;
                int r = c * 8 + lr;
                async16(wnh + (size_t)(j0 + r) * FDIM + k0 + lg * 8, &Bsh[c * 512 + lane * 8]);
            }
        }
        __syncthreads();
        #pragma unroll
        for (int ks = 0; ks < 2; ++ks) {
            int g = ks * 4 + (lane >> 4);
            f16x8 bfr[4];
            #pragma unroll
            for (int tn = 0; tn < 4; ++tn) {
                int j = wn * 64 + tn * 16 + (lane & 15);
                bfr[tn] = *(const f16x8*)&Bsh[sw_off(j, g)];
            }
            #pragma unroll
            for (int tm = 0; tm < 4; ++tm) {
                int m = wm * 64 + tm * 16 + (lane & 15);
                f16x8 afr = *(const f16x8*)&Ash[sw_off(m, g)];
                #pragma unroll
                for (int tn = 0; tn < 4; ++tn)
                    acc[tm][tn] = __builtin_amdgcn_mfma_f32_16x16x32_f16(afr, bfr[tn], acc[tm][tn], 0, 0, 0);
            }
        }
        __syncthreads();
    }

    // ---- epilogue A: bias + smooth_step -> LDS C-tile [row][col], stride 130 (conflict-free col reads)
    #pragma unroll
    for (int tn = 0; tn < 4; ++tn) {
        int col = wn * 64 + tn * 16 + (lane & 15);
        int c   = j0 + col;                 // c = t*64 + n
        int nn  = c & 63, tt = c >> 6;
        float bias = (nn < NODES) ? bn[nn * NTREE + tt] : 0.0f;
        #pragma unroll
        for (int tm = 0; tm < 4; ++tm) {
            #pragma unroll
            for (int r = 0; r < 4; ++r) {
                int row = wm * 64 + tm * 16 + (lane >> 4) * 4 + r;
                SH[row * 130 + col] = (f16)smooth_step_f(acc[tm][tn][r] + bias);
            }
        }
    }
    __syncthreads();

    // ---- epilogue B: prob fold. thread = (row, tree): 128 rows x 2 trees = 256 threads.
    {
        const int row = tid & 127;
        const int tr  = tid >> 7;                 // 0/1
        const f16* gp = &SH[row * 130 + tr * 64]; // 63 gates of this (row, tree)

        float pr[32];
        pr[0] = 1.0f;
        int bse = 0;
        #pragma unroll
        for (int lvl = 0; lvl < 5; ++lvl) {
            const int width = 1 << lvl;
            float sl[16];
            #pragma unroll
            for (int i = 0; i < width; ++i) sl[i] = (float)gp[bse + i];
            #pragma unroll
            for (int i = width - 1; i >= 0; --i) {
                float p = pr[i];
                pr[2 * i]     = p * sl[i];
                pr[2 * i + 1] = p * (1.0f - sl[i]);
            }
            bse += width;
        }
        f16x8 ov[8];
        #pragma unroll
        for (int i = 0; i < 32; ++i) {
            float s5 = (float)gp[31 + i];
            float p  = pr[i];
            ov[i >> 2][(i & 3) * 2]     = (f16)(p * s5);
            ov[i >> 2][(i & 3) * 2 + 1] = (f16)(p * (1.0f - s5));
        }
        // prob[row_g][tree_g*64 + l], contiguous 128 B per thread
        f16* dst = prob_out + (size_t)(row0 + row) * NJP + (size_t)(blockIdx.x * 2 + tr) * 64;
        #pragma unroll
        for (int c = 0; c < 8; ++c) ((f16x8*)dst)[c] = ov[c];
    }
}

// ---------------- phase 2: leaf GEMM (M=8192, N=128, K=4096), split-K via grid.y ----------------
__global__ __launch_bounds__(256, 4)
void leaf_gemm(const f16* __restrict__ prob, const f16* __restrict__ wlt,
               float* __restrict__ out, float* __restrict__ partial)
{
    __shared__ f16 SH[128 * 128];         // 32 KB staging A+B
    f16* Ash = SH;
    f16* Bsh = SH + 128 * 64;
    const int tid  = threadIdx.x;
    const int lane = tid & 63;
    const int w    = tid >> 6;
    const int wm   = w & 1;
    const int wn   = w >> 1;
    const int row0 = blockIdx.x * 128;
    const int nks  = gridDim.y;
    const int kch  = K2 / nks;
    const int kbeg = blockIdx.y * kch;
    float* dst = (nks == 1) ? out : partial + (size_t)blockIdx.y * BATCH * ODIM;

    const int lr = lane >> 3;
    const int lg = (lane & 7) ^ lr;
    f32x4 acc[4][4] = {};

    for (int k0 = kbeg; k0 < kbeg + kch; k0 += 64) {
        #pragma unroll
        for (int q = 0; q < 8; ++q) {
            int id = w * 8 + q;
            if (id < 16) {
                int r = id * 8 + lr;
                async16(prob + (size_t)(row0 + r) * NJP + k0 + lg * 8, &Ash[id * 512 + lane * 8]);
            } else {
                int c = id - 16;
                int o = c * 8 + lr;
                async16(wlt + (size_t)o * K2 + k0 + lg * 8, &Bsh[c * 512 + lane * 8]);
            }
        }
        __syncthreads();
        #pragma unroll
        for (int ks = 0; ks < 2; ++ks) {
            int g = ks * 4 + (lane >> 4);
            f16x8 bfr[4];
            #pragma unroll
            for (int tn = 0; tn < 4; ++tn) {
                int o = wn * 64 + tn * 16 + (lane & 15);
                bfr[tn] = *(const f16x8*)&Bsh[sw_off(o, g)];
            }
            #pragma unroll
            for (int tm = 0; tm < 4; ++tm) {
                int m = wm * 64 + tm * 16 + (lane & 15);
                f16x8 afr = *(const f16x8*)&Ash[sw_off(m, g)];
                #pragma unroll
                for (int tn = 0; tn < 4; ++tn)
                    acc[tm][tn] = __builtin_amdgcn_mfma_f32_16x16x32_f16(afr, bfr[tn], acc[tm][tn], 0, 0, 0);
            }
        }
        __syncthreads();
    }
    #pragma unroll
    for (int tn = 0; tn < 4; ++tn) {
        int o = wn * 64 + tn * 16 + (lane & 15);
        #pragma unroll
        for (int tm = 0; tm < 4; ++tm) {
            #pragma unroll
            for (int r = 0; r < 4; ++r) {
                int row = row0 + wm * 64 + tm * 16 + (lane >> 4) * 4 + r;
                dst[(size_t)row * ODIM + o] = acc[tm][tn][r];
            }
        }
    }
}

// ---------------- phase 3: split-K reduce ----------------
__global__ void reduce_kernel(const float* __restrict__ partial, float* __restrict__ out) {
    size_t i = ((size_t)blockIdx.x * blockDim.x + threadIdx.x) * 4;
    f32x4 a = *(const f32x4*)(partial + i);
    #pragma unroll
    for (int k = 1; k < KS; ++k)
        a += *(const f32x4*)(partial + (size_t)k * BATCH * ODIM + i);
    *(f32x4*)(out + i) = a;
}

// ---------------- fallback (round-1 proven kernel) ----------------
#define ROWS 8
__global__ __launch_bounds__(256, 2)
void soft_tree_fallback(const float* __restrict__ x, const float* __restrict__ Wn,
                        const float* __restrict__ bn, const float* __restrict__ Wl,
                        float* __restrict__ out)
{
    __shared__ __half s_lds[ROWS][NODES][NTREE];
    const int lane = threadIdx.x & 63;
    const int w    = threadIdx.x >> 6;
    const long row0 = (long)blockIdx.x * ROWS;
    for (int n = w; n < NODES; n += 4) {
        const float* wp = Wn + ((long)n * FDIM) * NTREE + lane;
        const float* xp = x + row0 * FDIM;
        float acc[ROWS];
        #pragma unroll
        for (int r = 0; r < ROWS; ++r) acc[r] = 0.0f;
        #pragma unroll 8
        for (int f = 0; f < FDIM; ++f) {
            float wv = wp[(long)f * NTREE];
            #pragma unroll
            for (int r = 0; r < ROWS; ++r)
                acc[r] = fmaf(xp[r * FDIM + f], wv, acc[r]);
        }
        float bias = bn[n * NTREE + lane];
        #pragma unroll
        for (int r = 0; r < ROWS; ++r)
            s_lds[r][n][lane] = __float2half(smooth_step_f(acc[r] + bias));
    }
    __syncthreads();
    const int r0 = w * 2, r1 = w * 2 + 1;
    float pr0[64], pr1[64];
    {
        pr0[0] = 1.0f; pr1[0] = 1.0f;
        int base = 0;
        #pragma unroll
        for (int lvl = 0; lvl < 6; ++lvl) {
            const int width = 1 << lvl;
            #pragma unroll
            for (int i = width - 1; i >= 0; --i) {
                float sa = __half2float(s_lds[r0][base + i][lane]);
                float sb = __half2float(s_lds[r1][base + i][lane]);
                float pa = pr0[i], pb = pr1[i];
                pr0[2 * i] = pa * sa; pr0[2 * i + 1] = pa * (1.0f - sa);
                pr1[2 * i] = pb * sb; pr1[2 * i + 1] = pb * (1.0f - sb);
            }
            base += width;
        }
    }
    for (int o = 0; o < ODIM; ++o) {
        const float* wlp = Wl + (long)o * NTREE + lane;
        float c0 = 0.0f, c1 = 0.0f;
        #pragma unroll
        for (int l = 0; l < 64; ++l) {
            float wv = wlp[(long)l * (ODIM * NTREE)];
            c0 = fmaf(pr0[l], wv, c0);
            c1 = fmaf(pr1[l], wv, c1);
        }
        #pragma unroll
        for (int off = 32; off > 0; off >>= 1) {
            c0 += __shfl_xor(c0, off, 64);
            c1 += __shfl_xor(c1, off, 64);
        }
        if (lane == 0) {
            out[(row0 + r0) * ODIM + o] = c0;
            out[(row0 + r1) * ODIM + o] = c1;
        }
    }
}

extern "C" void kernel_launch(void* const* d_in, const int* in_sizes, int n_in,
                              void* d_out, int out_size, void* d_ws, size_t ws_size,
                              hipStream_t stream) {
    const float* x  = (const float*)d_in[0];
    const float* Wn = (const float*)d_in[1];
    const float* bn = (const float*)d_in[2];
    const float* Wl = (const float*)d_in[3];
    float* out = (float*)d_out;

    if (ws_size < WS_MIN) {
        soft_tree_fallback<<<BATCH / ROWS, 256, 0, stream>>>(x, Wn, bn, Wl, out);
        return;
    }

    f16*   xh  = (f16*)((char*)d_ws + XH_OFF);
    f16*   wnh = (f16*)((char*)d_ws + WNH_OFF);
    f16*   wlt = (f16*)((char*)d_ws + WLT_OFF);
    f16*   sp  = (f16*)((char*)d_ws + SP_OFF);
    float* ps  = (float*)((char*)d_ws + PS_OFF);

    conv_x_kernel <<<(BATCH * FDIM) / (256 * 4), 256, 0, stream>>>(x, xh);
    conv_wl_kernel<<<ODIM, 256, 0, stream>>>(Wl, wlt);
    conv_wn_kernel<<<dim3(64, FDIM / 64), 256, 0, stream>>>(Wn, wnh);

    gemm_nodes<<<dim3(NJP / 128, BATCH / 128), 256, 0, stream>>>(xh, wnh, bn, sp);

    if (ws_size >= WS_FULL) {
        leaf_gemm<<<dim3(BATCH / 128, KS), 256, 0, stream>>>(sp, wlt, out, ps);
        reduce_kernel<<<(BATCH * ODIM) / (256 * 4), 256, 0, stream>>>(ps, out);
    } else {
        leaf_gemm<<<dim3(BATCH / 128, 1), 256, 0, stream>>>(sp, wlt, out, nullptr);
    }
}

// Round 8
// 176.786 us; speedup vs baseline: 1.3395x; 1.0702x over previous
//
#include <hip/hip_runtime.h>
#include <hip/hip_fp16.h>

#define BATCH 8192
#define FDIM  512
#define NTREE 64
#define NODES 63
#define ODIM  128
#define NJP   4096            // padded N: col c = t*64 + n, n=63 is pad
#define K2    4096            // leaf GEMM K: k = t*64 + l
#define KS    8               // leaf split-K factor

typedef _Float16 f16;
typedef _Float16 f16x2 __attribute__((ext_vector_type(2)));
typedef _Float16 f16x8 __attribute__((ext_vector_type(8)));
typedef float    f32x4 __attribute__((ext_vector_type(4)));

// ---------------- workspace layout (bytes) ----------------
#define XH_OFF   0
#define XH_SZ    ((size_t)BATCH*FDIM*2)        // 8.39 MB  x  f16 [b][f]
#define WNH_OFF  (XH_OFF + XH_SZ)
#define WNH_SZ   ((size_t)NJP*FDIM*2)          // 4.19 MB  Wn f16 [t*64+n][f]
#define WLT_OFF  (WNH_OFF + WNH_SZ)
#define WLT_SZ   ((size_t)ODIM*K2*2)           // 1.05 MB  Wl f16 [o][t*64+l]
#define SP_OFF   (WLT_OFF + WLT_SZ)
#define SP_SZ    ((size_t)BATCH*NJP*2)         // 67.1 MB  prob f16 [b][t*64+l]
#define PS_OFF   (SP_OFF + SP_SZ)
#define PS_SZ    ((size_t)KS*BATCH*ODIM*4)     // 33.6 MB  leaf split-K f32 partials
#define WS_MIN   (SP_OFF + SP_SZ)
#define WS_FULL  (PS_OFF + PS_SZ)

__device__ __forceinline__ float smooth_step_f(float t) {
    float tc = fminf(fmaxf(t, -0.5f), 0.5f);
    return fmaf(tc, fmaf(-2.0f * tc, tc, 1.5f), 0.5f);
}

__device__ __forceinline__ void async16(const void* g, void* l) {
    __builtin_amdgcn_global_load_lds((__attribute__((address_space(1))) void*)g,
                                     (__attribute__((address_space(3))) void*)l,
                                     16, 0, 0);
}

// swizzled f16 offset of (row, group g) in a [rows][64] tile staged as 1KB/8-row chunks
__device__ __forceinline__ int sw_off(int row, int g) {
    return ((row >> 3) * 512) + (((row & 7) * 8 + (g ^ (row & 7))) * 8);
}

// ---------------- conversions ----------------
__global__ void conv_x_kernel(const float* __restrict__ in, f16* __restrict__ out) {
    size_t i = ((size_t)blockIdx.x * blockDim.x + threadIdx.x) * 4;
    float4 v = *(const float4*)(in + i);
    f16* o = out + i;
    o[0] = (f16)v.x; o[1] = (f16)v.y; o[2] = (f16)v.z; o[3] = (f16)v.w;
}

// Wl[l][o][t] fp32 -> wlt[o][t*64+l] f16 ; one block per o
__global__ void conv_wl_kernel(const float* __restrict__ in, f16* __restrict__ out) {
    __shared__ f16 tile[64][72];          // [t][l], padded
    const int o    = blockIdx.x;          // 0..127
    const int lane = threadIdx.x & 63;    // t on read
    const int w    = threadIdx.x >> 6;
    #pragma unroll
    for (int lc = 0; lc < 16; ++lc) {
        int l = w * 16 + lc;
        tile[lane][l] = (f16)in[(size_t)l * (ODIM * NTREE) + o * 64 + lane];  // coalesced
    }
    __syncthreads();
    f16* orow = out + (size_t)o * K2;
    #pragma unroll
    for (int c = 0; c < 2; ++c) {
        int idx = (threadIdx.x * 2 + c) * 8;   // 0..4088
        int t = idx >> 6, l = idx & 63;
        f16x8 v;
        #pragma unroll
        for (int e = 0; e < 8; ++e) v[e] = tile[t][l + e];
        *(f16x8*)(orow + idx) = v;             // fully coalesced
    }
}

// Wn[n][f][t] fp32 -> wnh[(t*64+n)][f] f16 ; block n==63 zeros pad rows
__global__ void conv_wn_kernel(const float* __restrict__ wn, f16* __restrict__ out) {
    const int n    = blockIdx.x;          // 0..63 (63 = pad)
    const int f0   = blockIdx.y * 64;
    const int lane = threadIdx.x & 63;
    const int w    = threadIdx.x >> 6;
    if (n == NODES) {
        #pragma unroll
        for (int tc = 0; tc < 16; ++tc) {
            int t = w * 16 + tc;
            out[(size_t)(t * 64 + NODES) * FDIM + f0 + lane] = (f16)0.0f;
        }
        return;
    }
    __shared__ float tile[64][65];
    const float* src = wn + (size_t)n * (FDIM * NTREE);
    #pragma unroll
    for (int i = 0; i < 16; ++i) {
        int fl = w * 16 + i;
        tile[fl][lane] = src[(size_t)(f0 + fl) * NTREE + lane];
    }
    __syncthreads();
    #pragma unroll
    for (int i = 0; i < 16; ++i) {
        int t = w * 16 + i;
        out[(size_t)(t * 64 + n) * FDIM + f0 + lane] = (f16)tile[lane][t];
    }
}

// ---------------- phase 1: node GEMM + bias + smooth_step + PROB FOLD fused ----------------
// Tile = 128 rows x 128 cols = 2 complete trees. Epilogue folds gates -> leaf probs
// and writes prob (not s) to global. s never touches HBM.
__global__ __launch_bounds__(256, 3)
void gemm_nodes(const f16* __restrict__ xh, const f16* __restrict__ wnh,
                const float* __restrict__ bn, f16* __restrict__ prob_out)
{
    __shared__ f16 SH[128 * 130];         // 33.3 KB: staging A+B (32 KB), then C-tile [128][130]
    f16* Ash = SH;
    f16* Bsh = SH + 128 * 64;
    const int tid  = threadIdx.x;
    const int lane = tid & 63;
    const int w    = tid >> 6;
    const int wm   = w & 1;
    const int wn   = w >> 1;
    const int j0   = blockIdx.x * 128;    // cols j0..j0+127 = trees 2bx, 2bx+1 (all nodes)
    const int row0 = blockIdx.y * 128;

    const int lr = lane >> 3;
    const int lg = (lane & 7) ^ lr;
    f32x4 acc[4][4] = {};

    for (int k0 = 0; k0 < FDIM; k0 += 64) {
        #pragma unroll
        for (int q = 0; q < 8; ++q) {
            int id = w * 8 + q;
            if (id < 16) {
                int r = id * 8 + lr;
                async16(xh + (size_t)(row0 + r) * FDIM + k0 + lg * 8, &Ash[id * 512 + lane * 8]);
            } else {
                int c = id - 16;
                int r = c * 8 + lr;
                async16(wnh + (size_t)(j0 + r) * FDIM + k0 + lg * 8, &Bsh[c * 512 + lane * 8]);
            }
        }
        __syncthreads();
        #pragma unroll
        for (int ks = 0; ks < 2; ++ks) {
            int g = ks * 4 + (lane >> 4);
            f16x8 bfr[4];
            #pragma unroll
            for (int tn = 0; tn < 4; ++tn) {
                int j = wn * 64 + tn * 16 + (lane & 15);
                bfr[tn] = *(const f16x8*)&Bsh[sw_off(j, g)];
            }
            #pragma unroll
            for (int tm = 0; tm < 4; ++tm) {
                int m = wm * 64 + tm * 16 + (lane & 15);
                f16x8 afr = *(const f16x8*)&Ash[sw_off(m, g)];
                #pragma unroll
                for (int tn = 0; tn < 4; ++tn)
                    acc[tm][tn] = __builtin_amdgcn_mfma_f32_16x16x32_f16(afr, bfr[tn], acc[tm][tn], 0, 0, 0);
            }
        }
        __syncthreads();
    }

    // ---- epilogue A: bias + smooth_step -> LDS C-tile [row][col], stride 130
    // bank(row,col) = (row + col/2) mod 32 -> conflict-free col writes / row reads
    #pragma unroll
    for (int tn = 0; tn < 4; ++tn) {
        int col = wn * 64 + tn * 16 + (lane & 15);
        int c   = j0 + col;                 // c = t*64 + n
        int nn  = c & 63, tt = c >> 6;
        float bias = (nn < NODES) ? bn[nn * NTREE + tt] : 0.0f;
        #pragma unroll
        for (int tm = 0; tm < 4; ++tm) {
            #pragma unroll
            for (int r = 0; r < 4; ++r) {
                int row = wm * 64 + tm * 16 + (lane >> 4) * 4 + r;
                SH[row * 130 + col] = (f16)smooth_step_f(acc[tm][tn][r] + bias);
            }
        }
    }
    __syncthreads();

    // ---- epilogue B: prob fold. thread = (row, tree): 128 rows x 2 trees = 256 threads.
    // Gates are contiguous f16 (dword-aligned base): read as 32x f16x2 (ds_read_b32).
    {
        const int row = tid & 127;
        const int tr  = tid >> 7;                 // 0/1
        const f16* gp = &SH[row * 130 + tr * 64];

        float g[64];
        #pragma unroll
        for (int c = 0; c < 32; ++c) {
            f16x2 v = *(const f16x2*)(gp + 2 * c);
            g[2 * c]     = (float)v[0];
            g[2 * c + 1] = (float)v[1];
        }

        float pr[32];
        pr[0] = 1.0f;
        int bse = 0;
        #pragma unroll
        for (int lvl = 0; lvl < 5; ++lvl) {
            const int width = 1 << lvl;
            #pragma unroll
            for (int i = width - 1; i >= 0; --i) {
                float p = pr[i], s = g[bse + i];
                pr[2 * i]     = p * s;
                pr[2 * i + 1] = p * (1.0f - s);
            }
            bse += width;
        }
        f16x8 ov[8];
        #pragma unroll
        for (int i = 0; i < 32; ++i) {
            float s5 = g[31 + i];
            float p  = pr[i];
            ov[i >> 2][(i & 3) * 2]     = (f16)(p * s5);
            ov[i >> 2][(i & 3) * 2 + 1] = (f16)(p * (1.0f - s5));
        }
        // prob[row_g][tree_g*64 + l], contiguous 128 B per thread
        f16* dst = prob_out + (size_t)(row0 + row) * NJP + (size_t)(blockIdx.x * 2 + tr) * 64;
        #pragma unroll
        for (int c = 0; c < 8; ++c) ((f16x8*)dst)[c] = ov[c];
    }
}

// ---------------- phase 2: leaf GEMM (M=8192, N=128, K=4096), split-K via grid.y ----------------
__global__ __launch_bounds__(256, 4)
void leaf_gemm(const f16* __restrict__ prob, const f16* __restrict__ wlt,
               float* __restrict__ out, float* __restrict__ partial)
{
    __shared__ f16 SH[128 * 128];         // 32 KB staging A+B
    f16* Ash = SH;
    f16* Bsh = SH + 128 * 64;
    const int tid  = threadIdx.x;
    const int lane = tid & 63;
    const int w    = tid >> 6;
    const int wm   = w & 1;
    const int wn   = w >> 1;
    const int row0 = blockIdx.x * 128;
    const int nks  = gridDim.y;
    const int kch  = K2 / nks;
    const int kbeg = blockIdx.y * kch;
    float* dst = (nks == 1) ? out : partial + (size_t)blockIdx.y * BATCH * ODIM;

    const int lr = lane >> 3;
    const int lg = (lane & 7) ^ lr;
    f32x4 acc[4][4] = {};

    for (int k0 = kbeg; k0 < kbeg + kch; k0 += 64) {
        #pragma unroll
        for (int q = 0; q < 8; ++q) {
            int id = w * 8 + q;
            if (id < 16) {
                int r = id * 8 + lr;
                async16(prob + (size_t)(row0 + r) * NJP + k0 + lg * 8, &Ash[id * 512 + lane * 8]);
            } else {
                int c = id - 16;
                int o = c * 8 + lr;
                async16(wlt + (size_t)o * K2 + k0 + lg * 8, &Bsh[c * 512 + lane * 8]);
            }
        }
        __syncthreads();
        #pragma unroll
        for (int ks = 0; ks < 2; ++ks) {
            int g = ks * 4 + (lane >> 4);
            f16x8 bfr[4];
            #pragma unroll
            for (int tn = 0; tn < 4; ++tn) {
                int o = wn * 64 + tn * 16 + (lane & 15);
                bfr[tn] = *(const f16x8*)&Bsh[sw_off(o, g)];
            }
            #pragma unroll
            for (int tm = 0; tm < 4; ++tm) {
                int m = wm * 64 + tm * 16 + (lane & 15);
                f16x8 afr = *(const f16x8*)&Ash[sw_off(m, g)];
                #pragma unroll
                for (int tn = 0; tn < 4; ++tn)
                    acc[tm][tn] = __builtin_amdgcn_mfma_f32_16x16x32_f16(afr, bfr[tn], acc[tm][tn], 0, 0, 0);
            }
        }
        __syncthreads();
    }
    #pragma unroll
    for (int tn = 0; tn < 4; ++tn) {
        int o = wn * 64 + tn * 16 + (lane & 15);
        #pragma unroll
        for (int tm = 0; tm < 4; ++tm) {
            #pragma unroll
            for (int r = 0; r < 4; ++r) {
                int row = row0 + wm * 64 + tm * 16 + (lane >> 4) * 4 + r;
                dst[(size_t)row * ODIM + o] = acc[tm][tn][r];
            }
        }
    }
}

// ---------------- phase 3: split-K reduce ----------------
__global__ void reduce_kernel(const float* __restrict__ partial, float* __restrict__ out) {
    size_t i = ((size_t)blockIdx.x * blockDim.x + threadIdx.x) * 4;
    f32x4 a = *(const f32x4*)(partial + i);
    #pragma unroll
    for (int k = 1; k < KS; ++k)
        a += *(const f32x4*)(partial + (size_t)k * BATCH * ODIM + i);
    *(f32x4*)(out + i) = a;
}

// ---------------- fallback (round-1 proven kernel) ----------------
#define ROWS 8
__global__ __launch_bounds__(256, 2)
void soft_tree_fallback(const float* __restrict__ x, const float* __restrict__ Wn,
                        const float* __restrict__ bn, const float* __restrict__ Wl,
                        float* __restrict__ out)
{
    __shared__ __half s_lds[ROWS][NODES][NTREE];
    const int lane = threadIdx.x & 63;
    const int w    = threadIdx.x >> 6;
    const long row0 = (long)blockIdx.x * ROWS;
    for (int n = w; n < NODES; n += 4) {
        const float* wp = Wn + ((long)n * FDIM) * NTREE + lane;
        const float* xp = x + row0 * FDIM;
        float acc[ROWS];
        #pragma unroll
        for (int r = 0; r < ROWS; ++r) acc[r] = 0.0f;
        #pragma unroll 8
        for (int f = 0; f < FDIM; ++f) {
            float wv = wp[(long)f * NTREE];
            #pragma unroll
            for (int r = 0; r < ROWS; ++r)
                acc[r] = fmaf(xp[r * FDIM + f], wv, acc[r]);
        }
        float bias = bn[n * NTREE + lane];
        #pragma unroll
        for (int r = 0; r < ROWS; ++r)
            s_lds[r][n][lane] = __float2half(smooth_step_f(acc[r] + bias));
    }
    __syncthreads();
    const int r0 = w * 2, r1 = w * 2 + 1;
    float pr0[64], pr1[64];
    {
        pr0[0] = 1.0f; pr1[0] = 1.0f;
        int base = 0;
        #pragma unroll
        for (int lvl = 0; lvl < 6; ++lvl) {
            const int width = 1 << lvl;
            #pragma unroll
            for (int i = width - 1; i >= 0; --i) {
                float sa = __half2float(s_lds[r0][base + i][lane]);
                float sb = __half2float(s_lds[r1][base + i][lane]);
                float pa = pr0[i], pb = pr1[i];
                pr0[2 * i] = pa * sa; pr0[2 * i + 1] = pa * (1.0f - sa);
                pr1[2 * i] = pb * sb; pr1[2 * i + 1] = pb * (1.0f - sb);
            }
            base += width;
        }
    }
    for (int o = 0; o < ODIM; ++o) {
        const float* wlp = Wl + (long)o * NTREE + lane;
        float c0 = 0.0f, c1 = 0.0f;
        #pragma unroll
        for (int l = 0; l < 64; ++l) {
            float wv = wlp[(long)l * (ODIM * NTREE)];
            c0 = fmaf(pr0[l], wv, c0);
            c1 = fmaf(pr1[l], wv, c1);
        }
        #pragma unroll
        for (int off = 32; off > 0; off >>= 1) {
            c0 += __shfl_xor(c0, off, 64);
            c1 += __shfl_xor(c1, off, 64);
        }
        if (lane == 0) {
            out[(row0 + r0) * ODIM + o] = c0;
            out[(row0 + r1) * ODIM + o] = c1;
        }
    }
}

extern "C" void kernel_launch(void* const* d_in, const int* in_sizes, int n_in,
                              void* d_out, int out_size, void* d_ws, size_t ws_size,
                              hipStream_t stream) {
    const float* x  = (const float*)d_in[0];
    const float* Wn = (const float*)d_in[1];
    const float* bn = (const float*)d_in[2];
    const float* Wl = (const float*)d_in[3];
    float* out = (float*)d_out;

    if (ws_size < WS_MIN) {
        soft_tree_fallback<<<BATCH / ROWS, 256, 0, stream>>>(x, Wn, bn, Wl, out);
        return;
    }

    f16*   xh  = (f16*)((char*)d_ws + XH_OFF);
    f16*   wnh = (f16*)((char*)d_ws + WNH_OFF);
    f16*   wlt = (f16*)((char*)d_ws + WLT_OFF);
    f16*   sp  = (f16*)((char*)d_ws + SP_OFF);
    float* ps  = (float*)((char*)d_ws + PS_OFF);

    conv_x_kernel <<<(BATCH * FDIM) / (256 * 4), 256, 0, stream>>>(x, xh);
    conv_wl_kernel<<<ODIM, 256, 0, stream>>>(Wl, wlt);
    conv_wn_kernel<<<dim3(64, FDIM / 64), 256, 0, stream>>>(Wn, wnh);

    gemm_nodes<<<dim3(NJP / 128, BATCH / 128), 256, 0, stream>>>(xh, wnh, bn, sp);

    if (ws_size >= WS_FULL) {
        leaf_gemm<<<dim3(BATCH / 128, KS), 256, 0, stream>>>(sp, wlt, out, ps);
        reduce_kernel<<<(BATCH * ODIM) / (256 * 4), 256, 0, stream>>>(ps, out);
    } else {
        leaf_gemm<<<dim3(BATCH / 128, 1), 256, 0, stream>>>(sp, wlt, out, nullptr);
    }
}

// Round 9
// 160.146 us; speedup vs baseline: 1.4787x; 1.1039x over previous
//
#include <hip/hip_runtime.h>
#include <hip/hip_fp16.h>

#define BATCH 8192
#define FDIM  512
#define NTREE 64
#define NODES 63
#define ODIM  128
#define NJP   4096            // padded node-col space: c = t*64 + n (n=63 pad)
#define K2    4096            // leaf K: k = t*64 + l
#define TPG   8               // tree-pair groups (grid.y); 4 tree-pairs each

typedef _Float16 f16;
typedef _Float16 f16x2 __attribute__((ext_vector_type(2)));
typedef _Float16 f16x8 __attribute__((ext_vector_type(8)));
typedef float    f32x4 __attribute__((ext_vector_type(4)));

// ---------------- workspace layout (bytes) ----------------
#define XH_OFF   0
#define XH_SZ    ((size_t)BATCH*FDIM*2)        // 8.39 MB  x  f16 [b][f]
#define WNH_OFF  (XH_OFF + XH_SZ)
#define WNH_SZ   ((size_t)NJP*FDIM*2)          // 4.19 MB  Wn f16 [t*64+n][f]
#define WLT_OFF  (WNH_OFF + WNH_SZ)
#define WLT_SZ   ((size_t)ODIM*K2*2)           // 1.05 MB  Wl f16 [o][t*64+l]
#define PS_OFF   (WLT_OFF + WLT_SZ)
#define PS_SZ    ((size_t)TPG*BATCH*ODIM*4)    // 33.6 MB  f32 partials per tp-group
#define WS_NEEDED (PS_OFF + PS_SZ)

__device__ __forceinline__ float smooth_step_f(float t) {
    float tc = fminf(fmaxf(t, -0.5f), 0.5f);
    return fmaf(tc, fmaf(-2.0f * tc, tc, 1.5f), 0.5f);
}

__device__ __forceinline__ void async16(const void* g, void* l) {
    __builtin_amdgcn_global_load_lds((__attribute__((address_space(1))) void*)g,
                                     (__attribute__((address_space(3))) void*)l,
                                     16, 0, 0);
}

// swizzled f16 offset of (row, group g) in a [rows][64] tile staged as 1KB/8-row chunks
__device__ __forceinline__ int sw_off(int row, int g) {
    return ((row >> 3) * 512) + (((row & 7) * 8 + (g ^ (row & 7))) * 8);
}

// ---------------- conversions ----------------
__global__ void conv_x_kernel(const float* __restrict__ in, f16* __restrict__ out) {
    size_t i = ((size_t)blockIdx.x * blockDim.x + threadIdx.x) * 4;
    float4 v = *(const float4*)(in + i);
    f16* o = out + i;
    o[0] = (f16)v.x; o[1] = (f16)v.y; o[2] = (f16)v.z; o[3] = (f16)v.w;
}

// Wl[l][o][t] fp32 -> wlt[o][t*64+l] f16 ; one block per o
__global__ void conv_wl_kernel(const float* __restrict__ in, f16* __restrict__ out) {
    __shared__ f16 tile[64][72];          // [t][l], padded
    const int o    = blockIdx.x;          // 0..127
    const int lane = threadIdx.x & 63;    // t on read
    const int w    = threadIdx.x >> 6;
    #pragma unroll
    for (int lc = 0; lc < 16; ++lc) {
        int l = w * 16 + lc;
        tile[lane][l] = (f16)in[(size_t)l * (ODIM * NTREE) + o * 64 + lane];  // coalesced
    }
    __syncthreads();
    f16* orow = out + (size_t)o * K2;
    #pragma unroll
    for (int c = 0; c < 2; ++c) {
        int idx = (threadIdx.x * 2 + c) * 8;   // 0..4088
        int t = idx >> 6, l = idx & 63;
        f16x8 v;
        #pragma unroll
        for (int e = 0; e < 8; ++e) v[e] = tile[t][l + e];
        *(f16x8*)(orow + idx) = v;             // fully coalesced
    }
}

// Wn[n][f][t] fp32 -> wnh[(t*64+n)][f] f16 ; block n==63 zeros pad rows
__global__ void conv_wn_kernel(const float* __restrict__ wn, f16* __restrict__ out) {
    const int n    = blockIdx.x;          // 0..63 (63 = pad)
    const int f0   = blockIdx.y * 64;
    const int lane = threadIdx.x & 63;
    const int w    = threadIdx.x >> 6;
    if (n == NODES) {
        #pragma unroll
        for (int tc = 0; tc < 16; ++tc) {
            int t = w * 16 + tc;
            out[(size_t)(t * 64 + NODES) * FDIM + f0 + lane] = (f16)0.0f;
        }
        return;
    }
    __shared__ float tile[64][65];
    const float* src = wn + (size_t)n * (FDIM * NTREE);
    #pragma unroll
    for (int i = 0; i < 16; ++i) {
        int fl = w * 16 + i;
        tile[fl][lane] = src[(size_t)(f0 + fl) * NTREE + lane];
    }
    __syncthreads();
    #pragma unroll
    for (int i = 0; i < 16; ++i) {
        int t = w * 16 + i;
        out[(size_t)(t * 64 + n) * FDIM + f0 + lane] = (f16)tile[lane][t];
    }
}

// ---------------- fused: node GEMM + smooth_step + prob fold + leaf partial GEMM ----------------
// grid (64 rowblks, 8 tpgroups); each block: 4 tree-pairs sequentially, lacc persistent.
// LDS map (f16 idx): [0,8192) Ash / leaf-B half0 ; [8192,16384) Bsh / leaf-B half1 ;
//                    [16384, 33024) gate C-tile [128][130] -> reused as prob A-tiles (2 x 8192)
__global__ __launch_bounds__(256, 2)
void fused_tree(const f16* __restrict__ xh, const f16* __restrict__ wnh,
                const float* __restrict__ bn, const f16* __restrict__ wlt,
                float* __restrict__ partial)
{
    __shared__ f16 SH[33024];             // 66048 B
    f16* CT = SH + 16384;                 // gate C-tile, stride 130
    const int tid  = threadIdx.x;
    const int lane = tid & 63;
    const int w    = tid >> 6;
    const int wm   = w & 1;
    const int wn   = w >> 1;
    const int row0 = blockIdx.x * 128;
    const int tpg  = blockIdx.y;

    const int lr = lane >> 3;
    const int lg = (lane & 7) ^ lr;
    const int frow = tid & 127;           // fold: row
    const int ftr  = tid >> 7;            // fold: tree within pair (0/1)

    f32x4 lacc[4][4] = {};                // leaf accumulator, persists over tree-pairs

    for (int tpi = 0; tpi < 4; ++tpi) {
        const int tp = tpg * 4 + tpi;
        const int j0 = tp * 128;          // node-col base (2 trees)

        // ---- node GEMM: 128 rows x 128 cols x K=512 ----
        f32x4 acc[4][4] = {};
        for (int k0 = 0; k0 < FDIM; k0 += 64) {
            #pragma unroll
            for (int q = 0; q < 8; ++q) {
                int id = w * 8 + q;
                if (id < 16) {
                    int r = id * 8 + lr;
                    async16(xh + (size_t)(row0 + r) * FDIM + k0 + lg * 8, &SH[id * 512 + lane * 8]);
                } else {
                    int c = id - 16;
                    int r = c * 8 + lr;
                    async16(wnh + (size_t)(j0 + r) * FDIM + k0 + lg * 8, &SH[8192 + c * 512 + lane * 8]);
                }
            }
            __syncthreads();
            #pragma unroll
            for (int ks = 0; ks < 2; ++ks) {
                int g = ks * 4 + (lane >> 4);
                f16x8 bfr[4];
                #pragma unroll
                for (int tn = 0; tn < 4; ++tn) {
                    int j = wn * 64 + tn * 16 + (lane & 15);
                    bfr[tn] = *(const f16x8*)&SH[8192 + sw_off(j, g)];
                }
                #pragma unroll
                for (int tm = 0; tm < 4; ++tm) {
                    int m = wm * 64 + tm * 16 + (lane & 15);
                    f16x8 afr = *(const f16x8*)&SH[sw_off(m, g)];
                    #pragma unroll
                    for (int tn = 0; tn < 4; ++tn)
                        acc[tm][tn] = __builtin_amdgcn_mfma_f32_16x16x32_f16(afr, bfr[tn], acc[tm][tn], 0, 0, 0);
                }
            }
            __syncthreads();
        }

        // ---- stage leaf B-tile (Wl, 128 o x 128 k) into [0,32K) — region free after loop barrier
        #pragma unroll
        for (int q = 0; q < 8; ++q) {
            int id = w * 8 + q;            // 0..31 chunks: half h, chunk c
            int h = id >> 4, c = id & 15;
            int o = c * 8 + lr;
            async16(wlt + (size_t)o * K2 + j0 + h * 64 + lg * 8,
                    &SH[h * 8192 + c * 512 + lane * 8]);
        }

        // ---- gate epilogue: bias + smooth_step -> C-tile [row][130]
        #pragma unroll
        for (int tn = 0; tn < 4; ++tn) {
            int col = wn * 64 + tn * 16 + (lane & 15);
            int nn  = col & 63;                       // node index (j0 multiple of 64)
            int tt  = (j0 + col) >> 6;                // global tree
            float bias = (nn < NODES) ? bn[nn * NTREE + tt] : 0.0f;
            #pragma unroll
            for (int tm = 0; tm < 4; ++tm) {
                #pragma unroll
                for (int r = 0; r < 4; ++r) {
                    int row = wm * 64 + tm * 16 + (lane >> 4) * 4 + r;
                    CT[row * 130 + col] = (f16)smooth_step_f(acc[tm][tn][r] + bias);
                }
            }
        }
        __syncthreads();

        // ---- fold: thread = (frow, ftr). gates contiguous, 2-way-free ds_read_b32
        f16x8 ov[8];
        {
            const f16* gp = &CT[frow * 130 + ftr * 64];
            float g[64];
            #pragma unroll
            for (int c = 0; c < 32; ++c) {
                f16x2 v = *(const f16x2*)(gp + 2 * c);
                g[2 * c]     = (float)v[0];
                g[2 * c + 1] = (float)v[1];
            }
            float pr[32];
            pr[0] = 1.0f;
            int bse = 0;
            #pragma unroll
            for (int lvl = 0; lvl < 5; ++lvl) {
                const int width = 1 << lvl;
                #pragma unroll
                for (int i = width - 1; i >= 0; --i) {
                    float p = pr[i], s = g[bse + i];
                    pr[2 * i]     = p * s;
                    pr[2 * i + 1] = p * (1.0f - s);
                }
                bse += width;
            }
            #pragma unroll
            for (int i = 0; i < 32; ++i) {
                float s5 = g[31 + i];
                float p  = pr[i];
                ov[i >> 2][(i & 3) * 2]     = (f16)(p * s5);
                ov[i >> 2][(i & 3) * 2 + 1] = (f16)(p * (1.0f - s5));
            }
        }
        __syncthreads();   // all gate reads done before overwrite

        // ---- write prob A-tiles (chunk format) over the C-tile region
        #pragma unroll
        for (int g2 = 0; g2 < 8; ++g2)
            *(f16x8*)&SH[16384 + ftr * 8192 + sw_off(frow, g2)] = ov[g2];
        __syncthreads();   // A visible; barrier also drains vmcnt -> Wl B staged

        // ---- leaf partial GEMM: lacc += prob(128x128) * Wl^T(128x128)
        #pragma unroll
        for (int ks2 = 0; ks2 < 4; ++ks2) {
            int h  = ks2 >> 1;
            int gg = (ks2 & 1) * 4 + (lane >> 4);
            f16x8 bfr[4];
            #pragma unroll
            for (int tn = 0; tn < 4; ++tn) {
                int o = wn * 64 + tn * 16 + (lane & 15);
                bfr[tn] = *(const f16x8*)&SH[h * 8192 + sw_off(o, gg)];
            }
            #pragma unroll
            for (int tm = 0; tm < 4; ++tm) {
                int m = wm * 64 + tm * 16 + (lane & 15);
                f16x8 afr = *(const f16x8*)&SH[16384 + h * 8192 + sw_off(m, gg)];
                #pragma unroll
                for (int tn = 0; tn < 4; ++tn)
                    lacc[tm][tn] = __builtin_amdgcn_mfma_f32_16x16x32_f16(afr, bfr[tn], lacc[tm][tn], 0, 0, 0);
            }
        }
        __syncthreads();   // leaf reads done before next tree-pair's staging
    }

    // ---- write f32 partial for this tp-group
    float* dst = partial + (size_t)tpg * BATCH * ODIM;
    #pragma unroll
    for (int tn = 0; tn < 4; ++tn) {
        int o = wn * 64 + tn * 16 + (lane & 15);
        #pragma unroll
        for (int tm = 0; tm < 4; ++tm) {
            #pragma unroll
            for (int r = 0; r < 4; ++r) {
                int row = row0 + wm * 64 + tm * 16 + (lane >> 4) * 4 + r;
                dst[(size_t)row * ODIM + o] = lacc[tm][tn][r];
            }
        }
    }
}

// ---------------- split reduce over TPG partials ----------------
__global__ void reduce_kernel(const float* __restrict__ partial, float* __restrict__ out) {
    size_t i = ((size_t)blockIdx.x * blockDim.x + threadIdx.x) * 4;
    f32x4 a = *(const f32x4*)(partial + i);
    #pragma unroll
    for (int k = 1; k < TPG; ++k)
        a += *(const f32x4*)(partial + (size_t)k * BATCH * ODIM + i);
    *(f32x4*)(out + i) = a;
}

// ---------------- fallback (round-1 proven kernel) ----------------
#define ROWS 8
__global__ __launch_bounds__(256, 2)
void soft_tree_fallback(const float* __restrict__ x, const float* __restrict__ Wn,
                        const float* __restrict__ bn, const float* __restrict__ Wl,
                        float* __restrict__ out)
{
    __shared__ __half s_lds[ROWS][NODES][NTREE];
    const int lane = threadIdx.x & 63;
    const int w    = threadIdx.x >> 6;
    const long row0 = (long)blockIdx.x * ROWS;
    for (int n = w; n < NODES; n += 4) {
        const float* wp = Wn + ((long)n * FDIM) * NTREE + lane;
        const float* xp = x + row0 * FDIM;
        float acc[ROWS];
        #pragma unroll
        for (int r = 0; r < ROWS; ++r) acc[r] = 0.0f;
        #pragma unroll 8
        for (int f = 0; f < FDIM; ++f) {
            float wv = wp[(long)f * NTREE];
            #pragma unroll
            for (int r = 0; r < ROWS; ++r)
                acc[r] = fmaf(xp[r * FDIM + f], wv, acc[r]);
        }
        float bias = bn[n * NTREE + lane];
        #pragma unroll
        for (int r = 0; r < ROWS; ++r)
            s_lds[r][n][lane] = __float2half(smooth_step_f(acc[r] + bias));
    }
    __syncthreads();
    const int r0 = w * 2, r1 = w * 2 + 1;
    float pr0[64], pr1[64];
    {
        pr0[0] = 1.0f; pr1[0] = 1.0f;
        int base = 0;
        #pragma unroll
        for (int lvl = 0; lvl < 6; ++lvl) {
            const int width = 1 << lvl;
            #pragma unroll
            for (int i = width - 1; i >= 0; --i) {
                float sa = __half2float(s_lds[r0][base + i][lane]);
                float sb = __half2float(s_lds[r1][base + i][lane]);
                float pa = pr0[i], pb = pr1[i];
                pr0[2 * i] = pa * sa; pr0[2 * i + 1] = pa * (1.0f - sa);
                pr1[2 * i] = pb * sb; pr1[2 * i + 1] = pb * (1.0f - sb);
            }
            base += width;
        }
    }
    for (int o = 0; o < ODIM; ++o) {
        const float* wlp = Wl + (long)o * NTREE + lane;
        float c0 = 0.0f, c1 = 0.0f;
        #pragma unroll
        for (int l = 0; l < 64; ++l) {
            float wv = wlp[(long)l * (ODIM * NTREE)];
            c0 = fmaf(pr0[l], wv, c0);
            c1 = fmaf(pr1[l], wv, c1);
        }
        #pragma unroll
        for (int off = 32; off > 0; off >>= 1) {
            c0 += __shfl_xor(c0, off, 64);
            c1 += __shfl_xor(c1, off, 64);
        }
        if (lane == 0) {
            out[(row0 + r0) * ODIM + o] = c0;
            out[(row0 + r1) * ODIM + o] = c1;
        }
    }
}

extern "C" void kernel_launch(void* const* d_in, const int* in_sizes, int n_in,
                              void* d_out, int out_size, void* d_ws, size_t ws_size,
                              hipStream_t stream) {
    const float* x  = (const float*)d_in[0];
    const float* Wn = (const float*)d_in[1];
    const float* bn = (const float*)d_in[2];
    const float* Wl = (const float*)d_in[3];
    float* out = (float*)d_out;

    if (ws_size < WS_NEEDED) {
        soft_tree_fallback<<<BATCH / ROWS, 256, 0, stream>>>(x, Wn, bn, Wl, out);
        return;
    }

    f16*   xh  = (f16*)((char*)d_ws + XH_OFF);
    f16*   wnh = (f16*)((char*)d_ws + WNH_OFF);
    f16*   wlt = (f16*)((char*)d_ws + WLT_OFF);
    float* ps  = (float*)((char*)d_ws + PS_OFF);

    conv_x_kernel <<<(BATCH * FDIM) / (256 * 4), 256, 0, stream>>>(x, xh);
    conv_wl_kernel<<<ODIM, 256, 0, stream>>>(Wl, wlt);
    conv_wn_kernel<<<dim3(64, FDIM / 64), 256, 0, stream>>>(Wn, wnh);

    fused_tree<<<dim3(BATCH / 128, TPG), 256, 0, stream>>>(xh, wnh, bn, wlt, ps);
    reduce_kernel<<<(BATCH * ODIM) / (256 * 4), 256, 0, stream>>>(ps, out);
}